// Round 8
// baseline (529.191 us; speedup 1.0000x reference)
//
#include <hip/hip_runtime.h>
#include <hip/hip_bf16.h>

// TimeMoERouter: B=8 S=512 H=1024 E=8 TOPK=2 NHEADS=8 DH=128 CAP=1536
// Round 8: occupancy experiment. 64x64 tiles, 16KB LDS, ~110 VGPR,
// __launch_bounds__(256,4) => 4 blocks/CU (16 waves/CU, 2x prior TLP).
// Split-bf16 3-segment MFMA, A-only LDS dbuf, B frag-native, KBARRIER.
// fill0 folded into G5/G7/tr2 zero-tails; converts merged. 15 launches.

#define Hh 1024

typedef __attribute__((ext_vector_type(8))) short short8v;
typedef __attribute__((ext_vector_type(4))) float f32x4;

static __device__ __forceinline__ ushort f2bf(float x) {
  uint u = __float_as_uint(x);
  u += 0x7FFF + ((u >> 16) & 1);          // round-to-nearest-even
  return (ushort)(u >> 16);
}
static __device__ __forceinline__ float bf2f(ushort h) {
  return __uint_as_float(((uint)h) << 16);
}

// raw barrier: LDS-visibility only; leaves global prefetches in flight (T4)
#define KBARRIER() do { \
    __builtin_amdgcn_sched_barrier(0); \
    asm volatile("s_waitcnt lgkmcnt(0)" ::: "memory"); \
    __builtin_amdgcn_sched_barrier(0); \
    __builtin_amdgcn_s_barrier(); \
    __builtin_amdgcn_sched_barrier(0); \
  } while (0)

static __device__ __forceinline__ void ztail(char* zout, long long zbase,
                                             long long zlimit, long long zchunk,
                                             int lin, int t, int bdim) {
  if (zlimit > 0) {
    long long zo = zbase + (long long)lin * zchunk;
    if (zo < zlimit) {
      long long n16 = (zlimit - zo) >> 4;
      long long c16 = zchunk >> 4;
      if (n16 > c16) n16 = c16;
      float4* zp = (float4*)(zout + zo);
      float4 zz = make_float4(0.f, 0.f, 0.f, 0.f);
      for (long long i = t; i < n16; i += bdim) zp[i] = zz;
    }
  }
}

// ---------------- split-precision MFMA GEMM, 64x64 tiles ----------------
// C[m,n] = alpha * sum_k A[m,k]*B[n,k], segments (Ah,Bh)+(Al,Bh)+(Ah,Bl).
// A: bf16, row stride lda, hi col aHi+k, lo col aLo+k (LDS-staged, dbuf).
// Bf: frag-native [hl][BNT][BKC][64][8].
// EPI: 0 fp32 C; 1 split bf16 row-major (hi col n, lo col n+splitOff);
//      2 QKV: n0<1024 -> Q split row-major; <2048 -> Kf frags; else Vf.
// 4 waves (2x2), wave tile 32x32, 16x16x32 bf16 MFMA. LDS 16KB.
template<int EPI, bool RELU, bool HAS_BN, bool HAS_BSN>
__global__ __launch_bounds__(256, 4) void mgemm_k(
    const ushort* __restrict__ A, int lda, long long sAmaj, long long sAmin, int aHi, int aLo,
    const ushort* __restrict__ Bf, int BNT, int BKC, long long sBmaj, long long sBmin,
    float* __restrict__ Cf, ushort* __restrict__ Ch, int ldc, long long sCmaj, long long sCmin,
    int splitOff,
    ushort* __restrict__ pK, ushort* __restrict__ pV,
    int Kd, int zdiv,
    const float* __restrict__ bN, const float* __restrict__ bSN, int ldbs, int smod,
    float alpha,
    char* __restrict__ zout, long long zbase, long long zlimit, long long zchunk)
{
  // XCD-aware bijective swizzle (all grids are multiples of 8)
  int gx = gridDim.x, gy = gridDim.y;
  int lin = (blockIdx.z * gy + blockIdx.y) * gx + blockIdx.x;
  int nwg = gx * gy * gridDim.z;
  int cpx = nwg >> 3;
  int swz = (lin & 7) * cpx + (lin >> 3);
  int bz = swz / (gx * gy);
  int rem = swz - bz * (gx * gy);
  int by = rem / gx, bx = rem - by * gx;

  int zj = bz / zdiv, zi = bz - zj * zdiv;
  A += (size_t)zj * sAmaj + (size_t)zi * sAmin;
  const ushort* bfb = Bf + (size_t)zj * sBmaj + (size_t)zi * sBmin;
  long long coff = (long long)zj * sCmaj + (long long)zi * sCmin;

  int m0 = by * 64, n0 = bx * 64;

  __shared__ __align__(16) ushort smem[8192];   // 16KB: 2 bufs x {Ah 4K, Al 4K}

  int t = threadIdx.x;
  int l = t & 63, w = t >> 6;
  int wm = w >> 1, wn = w & 1;

  f32x4 acc[2][2];
#pragma unroll
  for (int i = 0; i < 2; ++i)
#pragma unroll
    for (int j = 0; j < 2; ++j) acc[i][j] = (f32x4){0.f, 0.f, 0.f, 0.f};

  // A staging: thread covers row srow (0..63), int4-slot sc (0..3)
  int srow = t >> 2;
  int sc = t & 3;
  const ushort* gAh = A + (size_t)(m0 + srow) * lda + aHi + sc * 8;
  const ushort* gAl = A + (size_t)(m0 + srow) * lda + aLo + sc * 8;
  int wo = (srow * 64 + sc * 16) ^ (((srow >> 1) & 7) << 4);

  // A fragment read offsets
  int aoff[2];
#pragma unroll
  for (int mi = 0; mi < 2; ++mi) {
    int row = wm * 32 + mi * 16 + (l & 15);
    aoff[mi] = (row * 64 + (l >> 4) * 16) ^ (((row >> 1) & 7) << 4);
  }

  // B frag pointers (2 nt per wave, hi and lo)
  const ushort* bph[2];
  const ushort* bpl[2];
  int ntg0 = (n0 >> 4) + wn * 2;
#pragma unroll
  for (int ni = 0; ni < 2; ++ni) {
    bph[ni] = bfb + ((size_t)(ntg0 + ni) * BKC) * 512 + l * 8;
    bpl[ni] = bfb + ((size_t)(BNT + ntg0 + ni) * BKC) * 512 + l * 8;
  }

  int4 a0h, a0l, a1h, a1l;
  short8v B0h[2], B0l[2], B1h[2], B1l[2];

#define LOADA0(s) { a0h = *(const int4*)(gAh + (s)*32); a0l = *(const int4*)(gAl + (s)*32); }
#define LOADA1(s) { a1h = *(const int4*)(gAh + (s)*32); a1l = *(const int4*)(gAl + (s)*32); }
#define STOREA(h, lo2, base) { char* nb = (char*)smem + (base); \
    *(int4*)(nb + wo) = h; *(int4*)(nb + 4096 + wo) = lo2; }
#define LOADB(BH, BL, s) { _Pragma("unroll") \
    for (int ni = 0; ni < 2; ++ni) { \
      BH[ni] = *(const short8v*)(bph[ni] + (size_t)(s) * 512); \
      BL[ni] = *(const short8v*)(bpl[ni] + (size_t)(s) * 512); } }
#define MFMA_STEP(ahb, alb, BH, BL) { \
    short8v ah[2], al[2]; \
    _Pragma("unroll") for (int mi = 0; mi < 2; ++mi) \
      ah[mi] = *(const short8v*)((char*)smem + (ahb) + aoff[mi]); \
    _Pragma("unroll") for (int mi = 0; mi < 2; ++mi) \
      al[mi] = *(const short8v*)((char*)smem + (alb) + aoff[mi]); \
    _Pragma("unroll") for (int ni = 0; ni < 2; ++ni) \
      _Pragma("unroll") for (int mi = 0; mi < 2; ++mi) \
        acc[mi][ni] = __builtin_amdgcn_mfma_f32_16x16x32_bf16(ah[mi], BH[ni], acc[mi][ni], 0, 0, 0); \
    _Pragma("unroll") for (int ni = 0; ni < 2; ++ni) \
      _Pragma("unroll") for (int mi = 0; mi < 2; ++mi) \
        acc[mi][ni] = __builtin_amdgcn_mfma_f32_16x16x32_bf16(al[mi], BH[ni], acc[mi][ni], 0, 0, 0); \
    _Pragma("unroll") for (int ni = 0; ni < 2; ++ni) \
      _Pragma("unroll") for (int mi = 0; mi < 2; ++mi) \
        acc[mi][ni] = __builtin_amdgcn_mfma_f32_16x16x32_bf16(ah[mi], BL[ni], acc[mi][ni], 0, 0, 0); }

  int nt = Kd >> 5;            // always even (>=4)
  LOADA0(0); LOADB(B0h, B0l, 0);
  LOADA1(1); LOADB(B1h, B1l, 1);
  STOREA(a0h, a0l, 0);
  KBARRIER();
  for (int s2 = 0; s2 < nt; s2 += 2) {
    if (s2 + 2 < nt) LOADA0(s2 + 2);
    MFMA_STEP(0, 4096, B0h, B0l);
    if (s2 + 2 < nt) LOADB(B0h, B0l, s2 + 2);
    STOREA(a1h, a1l, 8192);
    KBARRIER();
    if (s2 + 3 < nt) LOADA1(s2 + 3);
    MFMA_STEP(8192, 12288, B1h, B1l);
    if (s2 + 3 < nt) LOADB(B1h, B1l, s2 + 3);
    if (s2 + 2 < nt) STOREA(a0h, a0l, 0);
    KBARRIER();
  }
#undef LOADA0
#undef LOADA1
#undef STOREA
#undef LOADB
#undef MFMA_STEP

  // fold alpha + biases + relu into acc
#pragma unroll
  for (int mi = 0; mi < 2; ++mi)
#pragma unroll
    for (int j = 0; j < 4; ++j) {
      int m = m0 + wm * 32 + mi * 16 + (l >> 4) * 4 + j;
#pragma unroll
      for (int ni = 0; ni < 2; ++ni) {
        int n = n0 + wn * 32 + ni * 16 + (l & 15);
        float x = acc[mi][ni][j] * alpha;
        if (HAS_BN) x += bN[n];
        if (HAS_BSN) x += bSN[(size_t)(m % smod) * ldbs + n];
        if (RELU) x = fmaxf(x, 0.f);
        acc[mi][ni][j] = x;
      }
    }

  __syncthreads();   // all LDS k-loop reads done before epilogue reuse

  if (EPI == 0) {
    // fp32 LDS-bounce: [64][64] fp32 = 16KB, coalesced int4 stores
    float* Fs = (float*)smem;
#pragma unroll
    for (int mi = 0; mi < 2; ++mi)
#pragma unroll
      for (int j = 0; j < 4; ++j) {
        int r = wm * 32 + mi * 16 + (l >> 4) * 4 + j;
#pragma unroll
        for (int ni = 0; ni < 2; ++ni) {
          int c = wn * 32 + ni * 16 + (l & 15);
          *(float*)((char*)Fs + ((r * 256 + c * 4) ^ ((r & 7) << 4))) = acc[mi][ni][j];
        }
      }
    __syncthreads();
#pragma unroll
    for (int r4 = 0; r4 < 4; ++r4) {
      int idx = r4 * 256 + t;
      int row = idx >> 4, slot = idx & 15;
      int4 v = *(const int4*)((char*)Fs + ((row * 256 + slot * 16) ^ ((row & 7) << 4)));
      *(int4*)(Cf + coff + (size_t)(m0 + row) * ldc + n0 + slot * 4) = v;
    }
  } else {
    ushort* Es = smem;
    bool isQ = (EPI == 1) || (n0 < 1024);
    bool isK = (EPI == 2) && !isQ && (n0 < 2048);
    int bb = m0 >> 9, s0 = m0 & 511;
    int hh2 = isK ? ((n0 - 1024) >> 7) : ((n0 - 2048) >> 7);
    int dhalf = isK ? (((n0 - 1024) >> 6) & 1) : (((n0 - 2048) >> 6) & 1);
    size_t kvb = (size_t)(bb * 8 + hh2) * 131072;
#pragma unroll
    for (int pass = 0; pass < 2; ++pass) {
      if (!(EPI == 2 && !isQ && !isK)) {
        // row-major [64 rows][64 cols] ush = 8KB (Q and K)
#pragma unroll
        for (int mi = 0; mi < 2; ++mi)
#pragma unroll
          for (int j = 0; j < 4; ++j) {
            int lr = wm * 32 + mi * 16 + (l >> 4) * 4 + j;
#pragma unroll
            for (int ni = 0; ni < 2; ++ni) {
              int lcb = (wn * 32 + ni * 16 + (l & 15)) * 2;
              float x = acc[mi][ni][j];
              ushort h = f2bf(x);
              ushort vv = (pass == 0) ? h : f2bf(x - bf2f(h));
              *(ushort*)((char*)Es + ((lr * 128 + lcb) ^ ((lr & 7) << 4))) = vv;
            }
          }
      } else {
        // V: transposed [64 d][64 s] ush = 8KB
#pragma unroll
        for (int mi = 0; mi < 2; ++mi)
#pragma unroll
          for (int j = 0; j < 4; ++j) {
            int cc = (wm * 32 + mi * 16 + (l >> 4) * 4 + j) * 2;
#pragma unroll
            for (int ni = 0; ni < 2; ++ni) {
              int rr = wn * 32 + ni * 16 + (l & 15);
              float x = acc[mi][ni][j];
              ushort h = f2bf(x);
              ushort vv = (pass == 0) ? h : f2bf(x - bf2f(h));
              *(ushort*)((char*)Es + ((rr * 128 + cc) ^ ((rr & 7) << 4))) = vv;
            }
          }
      }
      __syncthreads();
      if (isQ) {
#pragma unroll
        for (int r = 0; r < 2; ++r) {
          int idx = r * 256 + t;
          int row = idx >> 3, cb = (idx & 7) * 16;
          int off = (pass == 0) ? 0 : splitOff;
          int4 v = *(const int4*)((char*)Es + ((row * 128 + cb) ^ ((row & 7) << 4)));
          *(int4*)((char*)(Ch + coff + (size_t)(m0 + row) * ldc + off + n0) + cb) = v;
        }
      } else if (isK) {
        // frags: st (4 s-tiles) x dc (2 32-d chunks)
#pragma unroll
        for (int sw = 0; sw < 2; ++sw) {
          int idx = sw * 256 + t;
          int f = idx >> 6, l2 = idx & 63;
          int st = f >> 1, dc = f & 1;
          int row = st * 16 + (l2 & 15);
          int colB = dc * 64 + ((l2 >> 4) << 4);
          short8v v = *(const short8v*)((char*)Es + ((row * 128 + colB) ^ ((row & 7) << 4)));
          int kc = dhalf * 2 + dc;
          *(short8v*)(pK + kvb + (size_t)((pass * 32 + (s0 >> 4) + st) * 4 + kc) * 512 + l2 * 8) = v;
        }
      } else {
        // frags: ntL (4 d-tiles) x sc2 (2 32-s chunks)
#pragma unroll
        for (int sw = 0; sw < 2; ++sw) {
          int idx = sw * 256 + t;
          int f = idx >> 6, l2 = idx & 63;
          int ntL = f >> 1, sc2 = f & 1;
          int row = ntL * 16 + (l2 & 15);
          int colB = sc2 * 64 + ((l2 >> 4) << 4);
          short8v v = *(const short8v*)((char*)Es + ((row * 128 + colB) ^ ((row & 7) << 4)));
          int ntd = dhalf * 4 + ntL;
          int kc = (s0 >> 5) + sc2;
          *(short8v*)(pV + kvb + (size_t)((pass * 8 + ntd) * 16 + kc) * 512 + l2 * 8) = v;
        }
      }
      if (pass == 0) __syncthreads();
    }
  }

  ztail(zout, zbase, zlimit, zchunk, lin, t, 256);
}

// ------- merged fp32 [N][K] -> frag-native hi|lo for all 5 weights -------
__global__ __launch_bounds__(64) void convall_k(
    const float* __restrict__ te_w1, const float* __restrict__ te_w2,
    const float* __restrict__ ain_w, const float* __restrict__ aout_w,
    const float* __restrict__ tr_w1, ushort* __restrict__ base)
{
  int kc = blockIdx.x, y = blockIdx.y, l = threadIdx.x;
  const float* W; int ldw, NT, nt2; ushort* dst;
  if (y < 64)       { W = te_w1;  ldw = 1026; NT = 64;  nt2 = y;       dst = base; }
  else if (y < 128) { W = te_w2;  ldw = 1024; NT = 64;  nt2 = y - 64;  dst = base + 2097152; }
  else if (y < 320) { W = ain_w;  ldw = 1024; NT = 192; nt2 = y - 128; dst = base + 4194304; }
  else if (y < 384) { W = aout_w; ldw = 1024; NT = 64;  nt2 = y - 320; dst = base + 10485760; }
  else              { W = tr_w1;  ldw = 1024; NT = 64;  nt2 = y - 384; dst = base + 12582912; }
  const float* src = W + (size_t)(nt2 * 16 + (l & 15)) * ldw + kc * 32 + ((l >> 4) << 3);
  ushort h8[8], l8[8];
#pragma unroll
  for (int j = 0; j < 8; ++j) {
    float x = src[j];
    h8[j] = f2bf(x);
    l8[j] = f2bf(x - bf2f(h8[j]));
  }
  *(int4*)(dst + ((size_t)nt2 * 32 + kc) * 512 + l * 8) = *(int4*)h8;
  *(int4*)(dst + ((size_t)(NT + nt2) * 32 + kc) * 512 + l * 8) = *(int4*)l8;
}

// ---------------- fp32 [N][K] -> bf16 hi|lo [N][2K] (row-major, for A) ----
__global__ __launch_bounds__(256) void convert_k(
    const float* __restrict__ W, int lda, ushort* __restrict__ Whl, int K)
{
  int r = blockIdx.x;
  int c = threadIdx.x * 4;
  const float* src = W + (size_t)r * lda + c;
  float x0 = src[0], x1 = src[1], x2 = src[2], x3 = src[3];
  ushort4 h, lo;
  h.x = f2bf(x0); lo.x = f2bf(x0 - bf2f(h.x));
  h.y = f2bf(x1); lo.y = f2bf(x1 - bf2f(h.y));
  h.z = f2bf(x2); lo.z = f2bf(x2 - bf2f(h.z));
  h.w = f2bf(x3); lo.w = f2bf(x3 - bf2f(h.w));
  ushort* dst = Whl + (size_t)r * 2 * K;
  *(ushort4*)&dst[c] = h;
  *(ushort4*)&dst[K + c] = lo;
}

// ---------------- seasonal / positional precompute (fp32) ----------------
__global__ __launch_bounds__(256) void precompute_k(
    const float* __restrict__ pos_emb,
    const float* __restrict__ se_w1, const float* __restrict__ se_b1,
    const float* __restrict__ se_w2, const float* __restrict__ se_b2,
    const float* __restrict__ sexp_w, const float* __restrict__ sexp_b,
    const float* __restrict__ te_w1, const float* __restrict__ te_b1,
    float* __restrict__ psea, float* __restrict__ bias1)
{
  int s = blockIdx.x, t = threadIdx.x;
  float ts = (float)s;
  float se = sinf(((ts * 2.0f) * 3.14159274101257324f) / 24.0f);
  __shared__ float l1[256], l2[256];
  l1[t] = fmaxf(se * se_w1[t] + se_b1[t], 0.f);
  __syncthreads();
  {
    float a = se_b2[t];
    const float* wr = se_w2 + (size_t)t * 256;
    for (int i = 0; i < 256; ++i) a += l1[i] * wr[i];
    l2[t] = a;
  }
  __syncthreads();
#pragma unroll
  for (int r = 0; r < 4; ++r) {
    int h = r * 256 + t;
    float v = sexp_b[h];
    const float* wr = sexp_w + (size_t)h * 256;
    for (int j = 0; j < 256; ++j) v += l2[j] * wr[j];
    psea[s * Hh + h] = pos_emb[s * Hh + h] + v;
    bias1[s * Hh + h] = te_b1[h] + ts * te_w1[(size_t)h * 1026 + 1024]
                                 + se * te_w1[(size_t)h * 1026 + 1025];
  }
}

// ------- softmax over split-bf16 score rows [hi512|lo512]; in-place -------
__global__ __launch_bounds__(256) void softmax2_k(ushort* __restrict__ S)
{
  int row = blockIdx.x * 4 + (threadIdx.x >> 6);
  int lane = threadIdx.x & 63;
  ushort* u = S + (size_t)row * 1024;
  int4 hv = *(const int4*)&u[lane * 8];
  int4 lv = *(const int4*)&u[512 + lane * 8];
  ushort h8[8], l8[8];
  *(int4*)h8 = hv; *(int4*)l8 = lv;
  float x[8];
#pragma unroll
  for (int j = 0; j < 8; ++j) x[j] = bf2f(h8[j]) + bf2f(l8[j]);
  float m = x[0];
#pragma unroll
  for (int j = 1; j < 8; ++j) m = fmaxf(m, x[j]);
#pragma unroll
  for (int off = 32; off; off >>= 1) m = fmaxf(m, __shfl_xor(m, off));
  float s = 0.f;
#pragma unroll
  for (int j = 0; j < 8; ++j) { x[j] = expf(x[j] - m); s += x[j]; }
#pragma unroll
  for (int off = 32; off; off >>= 1) s += __shfl_xor(s, off);
  float inv = 1.f / s;
#pragma unroll
  for (int j = 0; j < 8; ++j) {
    float p = x[j] * inv;
    h8[j] = f2bf(p);
    l8[j] = f2bf(p - bf2f(h8[j]));
  }
  *(int4*)&u[lane * 8] = *(int4*)h8;
  *(int4*)&u[512 + lane * 8] = *(int4*)l8;
}

// -------- logits = h1 @ tr_w2^T + b (N=8) + zero-tail over dead scratch ----
__global__ __launch_bounds__(256) void tr2_k(
    const float* __restrict__ h1, const float* __restrict__ w,
    const float* __restrict__ bias, float* __restrict__ logits,
    char* __restrict__ zout, long long zbase, long long zlimit, long long zchunk)
{
  int wid = threadIdx.x >> 6, lane = threadIdx.x & 63;
  int t = blockIdx.x * 4 + wid;
  const float* x = h1 + (size_t)t * Hh;
  float acc[8];
#pragma unroll
  for (int e = 0; e < 8; ++e) acc[e] = 0.f;
  for (int k = lane; k < Hh; k += 64) {
    float xv = x[k];
#pragma unroll
    for (int e = 0; e < 8; ++e) acc[e] += xv * w[e * Hh + k];
  }
#pragma unroll
  for (int e = 0; e < 8; ++e) {
#pragma unroll
    for (int off = 32; off; off >>= 1) acc[e] += __shfl_xor(acc[e], off);
  }
  if (lane == 0) {
#pragma unroll
    for (int e = 0; e < 8; ++e) logits[(size_t)t * 8 + e] = acc[e] + bias[e];
  }
  ztail(zout, zbase, zlimit, zchunk, blockIdx.x, threadIdx.x, 256);
}

// ---------------- zero fill (h1 region after tr2) ----------------
__global__ __launch_bounds__(256) void fill0_k(float4* __restrict__ p, long long n4)
{
  long long i = (long long)blockIdx.x * 256 + threadIdx.x;
  long long stride = (long long)gridDim.x * 256;
  float4 z = make_float4(0.f, 0.f, 0.f, 0.f);
  for (; i < n4; i += stride) p[i] = z;
}

// ---------------- router: softmax, top2, slot writes, partial p-sums -------
__global__ __launch_bounds__(256) void router_k(
    float* __restrict__ out, float* __restrict__ partials)
{
  int t = blockIdx.x * 256 + threadIdx.x;            // token 0..4095
  float* lg = out + 100663296 + (size_t)t * 8;       // logits (in-place -> probs)
  float p[8];
#pragma unroll
  for (int e = 0; e < 8; ++e) p[e] = lg[e];
  float m = p[0];
#pragma unroll
  for (int e = 1; e < 8; ++e) m = fmaxf(m, p[e]);
  float s = 0.f;
#pragma unroll
  for (int e = 0; e < 8; ++e) { p[e] = expf(p[e] - m); s += p[e]; }
  float inv = 1.f / s;
#pragma unroll
  for (int e = 0; e < 8; ++e) p[e] *= inv;
#pragma unroll
  for (int e = 0; e < 8; ++e) lg[e] = p[e];          // router_probs out

  int i0 = 0; float v0 = p[0];
#pragma unroll
  for (int e = 1; e < 8; ++e) if (p[e] > v0) { v0 = p[e]; i0 = e; }
  int i1 = -1; float v1 = -1.f;
#pragma unroll
  for (int e = 0; e < 8; ++e) if (e != i0 && p[e] > v1) { v1 = p[e]; i1 = e; }
  float wn = 1.f / (v0 + v1);
  size_t db = (size_t)t * (8 * 1536);
  out[db + (size_t)i0 * 1536] = 1.f;
  out[db + (size_t)i1 * 1536] = 1.f;
  out[50331648 + db + (size_t)i0 * 1536] = v0 * wn;
  out[50331648 + db + (size_t)i1 * 1536] = v1 * wn;

  __shared__ float red[256];
#pragma unroll
  for (int e = 0; e < 8; ++e) {
    red[threadIdx.x] = p[e];
    __syncthreads();
    for (int st = 128; st; st >>= 1) {
      if (threadIdx.x < st) red[threadIdx.x] += red[threadIdx.x + st];
      __syncthreads();
    }
    if (threadIdx.x == 0) partials[blockIdx.x * 8 + e] = red[0];
    __syncthreads();
  }
}

// ---------------- aux loss + cleanup of partials scratch ----------------
__global__ __launch_bounds__(64) void aux_k(float* __restrict__ partials,
                                            float* __restrict__ out)
{
  int lane = threadIdx.x;
  float v = 0.f;
  if (lane < 8) {
    float s = 0.f;
    for (int b = 0; b < 16; ++b) s += partials[b * 8 + lane];
    float pm = s / 4096.f;
    v = pm * logf(pm * 8.f + 1e-9f);
  }
#pragma unroll
  for (int off = 4; off; off >>= 1) v += __shfl_xor(v, off);
  if (lane == 0) out[100696064] = v;
  partials[lane] = 0.f;
  partials[64 + lane] = 0.f;
}

extern "C" void kernel_launch(void* const* d_in, const int* in_sizes, int n_in,
                              void* d_out, int out_size, void* d_ws, size_t ws_size,
                              hipStream_t stream)
{
  const float* hidden = (const float*)d_in[0];
  const float* pos_emb = (const float*)d_in[1];
  const float* se_w1 = (const float*)d_in[2];
  const float* se_b1 = (const float*)d_in[3];
  const float* se_w2 = (const float*)d_in[4];
  const float* se_b2 = (const float*)d_in[5];
  const float* sexp_w = (const float*)d_in[6];
  const float* sexp_b = (const float*)d_in[7];
  const float* te_w1 = (const float*)d_in[8];
  const float* te_b1 = (const float*)d_in[9];
  const float* te_w2 = (const float*)d_in[10];
  const float* te_b2 = (const float*)d_in[11];
  const float* ain_w = (const float*)d_in[12];
  const float* ain_b = (const float*)d_in[13];
  const float* aout_w = (const float*)d_in[14];
  const float* aout_b = (const float*)d_in[15];
  const float* tr_w1 = (const float*)d_in[16];
  const float* tr_b1 = (const float*)d_in[17];
  const float* tr_w2 = (const float*)d_in[18];
  const float* tr_b2 = (const float*)d_in[19];
  float* out = (float*)d_out;
  char* ob = (char*)d_out;

  // Combine-half arena [COMB, COMB+201326592). Dispatch half zeroed by
  // G1/G2/G3/G6 tails; combine half by G5/G7/tr2 tails + fill0 (h1 region).
  const long long COMB = 201326592LL;
  ushort* Wbase = (ushort*)(ob + COMB);             // W1f/W2f/Waf/Wof/Wtf 28MB
  float*  psea = (float*)(ob + COMB + 29360128);    // 2MB
  float*  bias1= (float*)(ob + COMB + 31457280);    // 2MB
  ushort* attno= (ushort*)(ob + COMB + 33554432);   // 16MB (enc1 before G5)
  ushort* enc1 = (ushort*)(ob + COMB + 33554432);
  ushort* encf = (ushort*)(ob + COMB + 50331648);   // 16MB (enc2 before G6)
  ushort* enc2 = (ushort*)(ob + COMB + 50331648);
  ushort* qbuf = (ushort*)(ob + COMB + 67108864);   // 16MB
  ushort* Kf   = (ushort*)(ob + COMB + 83886080);   // 16MB
  ushort* Vf   = (ushort*)(ob + COMB + 100663296);  // 16MB
  ushort* scorS= (ushort*)(ob + COMB + 117440512);  // 32MB split scores -> P
  ushort* hid2 = (ushort*)(ob + COMB + 150994944);  // 16MB (h1 after G7)
  float*  h1   = (float*)(ob + COMB + 150994944);
  float*  parts= (float*)(ob + COMB + 167772160);   // 512B
  float*  lgts = out + 100663296;                   // logits -> probs region

  convall_k<<<dim3(32, 448), 64, 0, stream>>>(te_w1, te_w2, ain_w, aout_w, tr_w1, Wbase);
  convert_k<<<4096, 256, 0, stream>>>(hidden, 1024, hid2, 1024);
  precompute_k<<<512, 256, 0, stream>>>(pos_emb, se_w1, se_b1, se_w2, se_b2,
                                        sexp_w, sexp_b, te_w1, te_b1, psea, bias1);

  // G1: enc1 = relu(hidden @ te_w1'^T + bias1[s])   [zeros disp 0..32MiB)
  mgemm_k<1, true, false, true><<<dim3(16, 64, 1), 256, 0, stream>>>(
      hid2, 2048, 0, 0, 0, 1024,
      Wbase, 64, 32, 0, 0,
      nullptr, enc1, 2048, 0, 0, 1024, nullptr, nullptr,
      1024, 1, nullptr, bias1, 1024, 512, 1.f,
      ob, 0LL, 33554432LL, 32768LL);

  // G2: enc2 = enc1 @ te_w2^T + te_b2 + psea[s]     [zeros disp 32..64MiB)
  mgemm_k<1, false, true, true><<<dim3(16, 64, 1), 256, 0, stream>>>(
      enc1, 2048, 0, 0, 0, 1024,
      Wbase + 2097152, 64, 32, 0, 0,
      nullptr, enc2, 2048, 0, 0, 1024, nullptr, nullptr,
      1024, 1, te_b2, psea, 1024, 512, 1.f,
      ob, 33554432LL, 67108864LL, 32768LL);

  // G3: qkv = enc2 @ attn_in_w^T + attn_in_b        [zeros disp 64..160MiB)
  mgemm_k<2, false, true, false><<<dim3(48, 64, 1), 256, 0, stream>>>(
      enc2, 2048, 0, 0, 0, 1024,
      Wbase + 4194304, 192, 32, 0, 0,
      nullptr, qbuf, 2048, 0, 0, 1024, Kf, Vf,
      1024, 1, ain_b, nullptr, 1, 1, 1.f,
      ob, 67108864LL, 167772160LL, 32768LL);

  // G4: scores = Q K^T / sqrt(128)  (split-bf16 into scorS)
  mgemm_k<1, false, false, false><<<dim3(8, 8, 64), 256, 0, stream>>>(
      qbuf, 2048, 1048576, 128, 0, 1024,
      Kf, 32, 4, 1048576, 131072,
      nullptr, scorS, 1024, 4194304, 524288, 512, nullptr, nullptr,
      128, 8, nullptr, nullptr, 1, 1, 0.08838834764831845f,
      nullptr, 0LL, 0LL, 0LL);

  softmax2_k<<<8192, 256, 0, stream>>>(scorS);

  // G5: attno = P @ V          [zeros comb qbuf+Kf 67.1..100.7MB)
  mgemm_k<1, false, false, false><<<dim3(2, 8, 64), 256, 0, stream>>>(
      scorS, 1024, 4194304, 524288, 0, 512,
      Vf, 8, 16, 1048576, 131072,
      nullptr, attno, 2048, 1048576, 128, 1024, nullptr, nullptr,
      512, 8, nullptr, nullptr, 1, 1, 1.f,
      ob, COMB + 67108864LL, COMB + 100663296LL, 32768LL);

  // G6: encf = attno @ attn_out_w^T + attn_out_b    [zeros disp 160..192MiB)
  mgemm_k<1, false, true, false><<<dim3(16, 64, 1), 256, 0, stream>>>(
      attno, 2048, 0, 0, 0, 1024,
      Wbase + 10485760, 64, 32, 0, 0,
      nullptr, encf, 2048, 0, 0, 1024, nullptr, nullptr,
      1024, 1, aout_b, nullptr, 1, 1, 1.f,
      ob, 167772160LL, 201326592LL, 32768LL);

  // G7: h1 = relu(encf @ tr_w1^T + tr_b1)  [zeros comb Vf+scorS 100.7..151MB)
  mgemm_k<0, true, true, false><<<dim3(16, 64, 1), 256, 0, stream>>>(
      encf, 2048, 0, 0, 0, 1024,
      Wbase + 12582912, 64, 32, 0, 0,
      h1, nullptr, 1024, 0, 0, 0, nullptr, nullptr,
      1024, 1, tr_b1, nullptr, 1, 1, 1.f,
      ob, COMB + 100663296LL, COMB + 150994944LL, 49152LL);

  // tr2: logits  [zeros comb W-region+attno+encf 0..67.1MB)
  tr2_k<<<1024, 256, 0, stream>>>(h1, tr_w2, tr_b2, lgts,
                                  ob, COMB + 0LL, COMB + 67108864LL, 65536LL);

  // remaining combine region: h1 + parts + spare [151..201.3MB)
  fill0_k<<<2048, 256, 0, stream>>>((float4*)(ob + COMB + 150994944), 3145728LL);

  router_k<<<16, 256, 0, stream>>>(out, parts);
  aux_k<<<1, 64, 0, stream>>>(parts, out);
}